// Round 8
// baseline (804.689 us; speedup 1.0000x reference)
//
#include <hip/hip_runtime.h>
#include <hip/hip_bf16.h>

#define NTOK 512
#define HDIM 2880
#define NGU  5760
#define NEXP 16
#define KSTEPS 90   // 2880 / 32
#define MT 160      // m-tile rows
#define MFR 10      // MT/16 m-fragments
#define NITEM_G 736             // 23 fc-tiles x 2 m-tiles x 16 experts
#define NITEM_ALL (2*NITEM_G)

typedef float  f32x4  __attribute__((ext_vector_type(4)));
typedef float  f32x2  __attribute__((ext_vector_type(2)));
typedef short  bf16x8 __attribute__((ext_vector_type(8)));

__device__ __forceinline__ unsigned short f2bf(float f) {
  union { float f; unsigned u; } a; a.f = f;
  unsigned r = a.u + 0x7FFFu + ((a.u >> 16) & 1u);   // RNE truncate to bf16
  return (unsigned short)(r >> 16);
}

// Barrier that does NOT drain vmcnt: LDS-only wait + raw s_barrier.
__device__ __forceinline__ void lds_barrier() {
  asm volatile("s_waitcnt lgkmcnt(0)" ::: "memory");
  __builtin_amdgcn_s_barrier();
  asm volatile("" ::: "memory");
}

// ---------------- control kernels ----------------

__global__ __launch_bounds__(256) void k_router(
    const float* __restrict__ x, const float* __restrict__ rw,
    const float* __restrict__ rb, int* __restrict__ counts,
    int* __restrict__ top_e, float* __restrict__ top_w)
{
  const int t = blockIdx.x;
  const int tid = threadIdx.x;
  __shared__ float red[256][17];
  float acc[NEXP];
#pragma unroll
  for (int e = 0; e < NEXP; ++e) acc[e] = 0.f;
  const float* xr = x + (size_t)t * HDIM;
  for (int h = tid; h < HDIM; h += 256) {
    float xv = xr[h];
    const f32x4* wr = (const f32x4*)(rw + (size_t)h * NEXP);
#pragma unroll
    for (int q = 0; q < 4; ++q) {
      f32x4 w = wr[q];
#pragma unroll
      for (int j = 0; j < 4; ++j) acc[q*4+j] += xv * w[j];
    }
  }
#pragma unroll
  for (int e = 0; e < NEXP; ++e) red[tid][e] = acc[e];
  __syncthreads();
  for (int s = 128; s > 0; s >>= 1) {
    if (tid < s) {
#pragma unroll
      for (int e = 0; e < NEXP; ++e) red[tid][e] += red[tid + s][e];
    }
    __syncthreads();
  }
  if (tid == 0) {
    float v[NEXP];
#pragma unroll
    for (int e = 0; e < NEXP; ++e) v[e] = red[0][e] + rb[e];
    int mask = 0; float tv[4]; int ti[4];
    for (int k = 0; k < 4; ++k) {
      float best = -3.4e38f; int bi = 0;
      for (int e = 0; e < NEXP; ++e)
        if (!((mask >> e) & 1) && v[e] > best) { best = v[e]; bi = e; }
      mask |= 1 << bi; tv[k] = best; ti[k] = bi;
    }
    float s = 0.f, ex[4];
    for (int k = 0; k < 4; ++k) { ex[k] = __expf(tv[k] - tv[0]); s += ex[k]; }
    float inv = 1.f / s;
    for (int k = 0; k < 4; ++k) {
      top_e[t*4+k] = ti[k];
      top_w[t*4+k] = ex[k] * inv;
      atomicAdd(&counts[ti[k]], 1);
    }
  }
}

// one wave per expert; deterministic compaction; prefix-scan folded in.
// Also zeroes the fused kernel's queue head and per-expert done counters.
__global__ __launch_bounds__(64) void k_fill(
    const int* __restrict__ top_e, const float* __restrict__ top_w,
    const int* __restrict__ counts, int* __restrict__ seg,
    int* __restrict__ pair_tok, float* __restrict__ pair_w,
    int* __restrict__ qhead, int* __restrict__ done)
{
  const int e = blockIdx.x;
  const int lane = threadIdx.x;
  if (lane == 1) done[e] = 0;
  if (e == 0 && lane == 2) *qhead = 0;
  int base = 0;
  for (int i = 0; i < e; ++i) base += counts[i];
  if (lane == 0) {
    seg[e] = base;
    if (e == NEXP - 1) seg[NEXP] = base + counts[e];
  }
  for (int t0 = 0; t0 < NTOK; t0 += 64) {
    int t = t0 + lane;
    int my = -1;
#pragma unroll
    for (int k = 0; k < 4; ++k) if (top_e[t*4+k] == e) my = k;
    unsigned long long m = __ballot(my >= 0);
    if (my >= 0) {
      int pre = __popcll(m & ((1ull << lane) - 1ull));
      pair_tok[base + pre] = t;
      pair_w[base + pre] = top_w[t*4+my];
    }
    base += (int)__popcll(m);
  }
}

// x (f32) -> xb (bf16), once; block 0 also zeroes counts (runs before router)
__global__ __launch_bounds__(256) void k_xbf16(
    const float* __restrict__ x, unsigned short* __restrict__ xb,
    int* __restrict__ counts)
{
  if (blockIdx.x == 0 && threadIdx.x < NEXP) counts[threadIdx.x] = 0;
  int i = (blockIdx.x * 256 + threadIdx.x) * 8;
  f32x4 a = *(const f32x4*)(x + i);
  f32x4 b = *(const f32x4*)(x + i + 4);
  bf16x8 o;
#pragma unroll
  for (int j = 0; j < 4; ++j) { o[j] = (short)f2bf(a[j]); o[4+j] = (short)f2bf(b[j]); }
  *(bf16x8*)(xb + i) = o;
}

// out[t][h] = sum_k w_k * down_b[e_k][h]  (zero-init + down bias)
__global__ __launch_bounds__(256) void k_outinit(
    const int* __restrict__ top_e, const float* __restrict__ top_w,
    const float* __restrict__ db, float* __restrict__ out)
{
  const int t = blockIdx.x;
  const int tid = threadIdx.x;
  const int e0 = top_e[t*4+0], e1 = top_e[t*4+1], e2 = top_e[t*4+2], e3 = top_e[t*4+3];
  const float w0 = top_w[t*4+0], w1 = top_w[t*4+1], w2 = top_w[t*4+2], w3 = top_w[t*4+3];
  const float* b0 = db + (size_t)e0 * HDIM;
  const float* b1 = db + (size_t)e1 * HDIM;
  const float* b2 = db + (size_t)e2 * HDIM;
  const float* b3 = db + (size_t)e3 * HDIM;
  for (int h = tid; h < HDIM; h += 256)
    out[(size_t)t*HDIM + h] = w0*b0[h] + w1*b1[h] + w2*b2[h] + w3*b3[h];
}

// ---------------- fused gate_up + down, dynamic work queue ----------------
// 512 blocks pull items: ids [0,736) = gate_up (e-major), [736,1472) = down
// (e-major). Down items spin on done[e] (release/acquire, device scope).
// Deadlock-free: all gu items are claimed before any dn item is claimed, and
// a claimed gu item is actively running -> every dn spin has a live producer.
__global__ __launch_bounds__(256, 2) void k_fused(
    const unsigned short* __restrict__ xb, const float* __restrict__ gw,
    const float* __restrict__ gb, const float* __restrict__ dw,
    const int* __restrict__ seg, const int* __restrict__ pair_tok,
    const float* __restrict__ pair_w, unsigned short* __restrict__ act,
    float* __restrict__ out, int* __restrict__ qhead, int* __restrict__ done)
{
  __shared__ unsigned short Alds[2][MT][40];
  __shared__ int s_id;
  const int tid = threadIdx.x;
  const int lane = tid & 63;
  const int wid = tid >> 6;
  const int l15 = lane & 15, lg = lane >> 4;
  const int r0 = tid >> 1, h0 = tid & 1;
  const int r1 = (tid + 256) >> 1, h1 = tid & 1;

  for (;;) {
    __syncthreads();
    if (tid == 0) s_id = atomicAdd(qhead, 1);
    __syncthreads();
    const int id = s_id;
    if (id >= NITEM_ALL) break;

    const bool is_dn = id >= NITEM_G;
    const int rid = is_dn ? id - NITEM_G : id;
    const int e  = rid / 46;
    const int y  = (rid % 46) / 23;
    const int ct = rid % 23;
    const int segs = seg[e];
    const int n_e = seg[e+1] - segs;
    const int m0 = y * MT;
    if (m0 >= n_e) continue;               // empty item (not counted in target)

    if (!is_dn) {
      // ================= gate_up item =================
      const int fcb = ct * 128 + wid * 32;
      const int fcE = fcb + 2*l15;
      const int colf = min(2*fcb + 4*l15, NGU - 4);
      const float* Bq = gw + (size_t)e * HDIM * NGU + colf + (size_t)lg * 8 * NGU;

      const unsigned short* sp0 = nullptr;
      const unsigned short* sp1 = nullptr;
      if (m0 + r0 < n_e) sp0 = xb + (size_t)pair_tok[segs + m0 + r0] * HDIM + h0*16;
      else sp0 = nullptr;
      if (tid < 2*MT - 256 && m0 + r1 < n_e)
        sp1 = xb + (size_t)pair_tok[segs + m0 + r1] * HDIM + h1*16;

      f32x4 accgE[MFR], accuE[MFR], accgO[MFR], accuO[MFR];
      {
        f32x4 b = __builtin_nontemporal_load((const f32x4*)(gb + (size_t)e * NGU + colf));
#pragma unroll
        for (int m = 0; m < MFR; ++m)
#pragma unroll
          for (int r = 0; r < 4; ++r) {
            accgE[m][r] = b[0]; accuE[m][r] = b[1];
            accgO[m][r] = b[2]; accuO[m][r] = b[3];
          }
      }

      auto stage = [&](int ks, int b) {
        bf16x8 z = {0,0,0,0,0,0,0,0};
        bf16x8 v0 = z, v1 = z;
        if (sp0) { v0 = *(const bf16x8*)(sp0 + ks*32); v1 = *(const bf16x8*)(sp0 + ks*32 + 8); }
        *(bf16x8*)&Alds[b][r0][h0*16]     = v0;
        *(bf16x8*)&Alds[b][r0][h0*16 + 8] = v1;
        if (tid < 2*MT - 256) {
          bf16x8 w0 = z, w1 = z;
          if (sp1) { w0 = *(const bf16x8*)(sp1 + ks*32); w1 = *(const bf16x8*)(sp1 + ks*32 + 8); }
          *(bf16x8*)&Alds[b][r1][h1*16]     = w0;
          *(bf16x8*)&Alds[b][r1][h1*16 + 8] = w1;
        }
      };

      f32x4 bA[8];
      auto loadB = [&](int ks) {
        const float* bp = Bq + (size_t)ks * 32 * NGU;
#pragma unroll
        for (int j = 0; j < 8; ++j)
          bA[j] = __builtin_nontemporal_load((const f32x4*)(bp + (size_t)j * NGU));
      };

      loadB(0);
      stage(0, 0);
      lds_barrier();
      int buf = 0;

      for (int ks = 0; ks < KSTEPS; ++ks) {
        if (ks + 1 < KSTEPS) stage(ks + 1, buf ^ 1);
        bf16x8 bgE, buE, bgO, buO;
#pragma unroll
        for (int j = 0; j < 8; ++j) {
          bgE[j] = (short)f2bf(bA[j][0]); buE[j] = (short)f2bf(bA[j][1]);
          bgO[j] = (short)f2bf(bA[j][2]); buO[j] = (short)f2bf(bA[j][3]);
        }
        if (ks + 1 < KSTEPS) loadB(ks + 1);
#pragma unroll
        for (int m = 0; m < MFR; ++m) {
          bf16x8 a = *(const bf16x8*)&Alds[buf][m*16 + l15][lg*8];
          accgE[m] = __builtin_amdgcn_mfma_f32_16x16x32_bf16(a, bgE, accgE[m], 0, 0, 0);
          accuE[m] = __builtin_amdgcn_mfma_f32_16x16x32_bf16(a, buE, accuE[m], 0, 0, 0);
          accgO[m] = __builtin_amdgcn_mfma_f32_16x16x32_bf16(a, bgO, accgO[m], 0, 0, 0);
          accuO[m] = __builtin_amdgcn_mfma_f32_16x16x32_bf16(a, buO, accuO[m], 0, 0, 0);
        }
        lds_barrier();
        buf ^= 1;
      }

      if (fcE < HDIM) {
#pragma unroll
        for (int m = 0; m < MFR; ++m) {
#pragma unroll
          for (int r = 0; r < 4; ++r) {
            int grow = m0 + m*16 + lg*4 + r;
            if (grow < n_e) {
              float pw = pair_w[segs + grow];
              float gE = fminf(accgE[m][r], 7.f);
              float uE = fminf(fmaxf(accuE[m][r], -7.f), 7.f);
              float avE = (uE + 1.f) * (gE / (1.f + __expf(-1.702f * gE))) * pw;
              float gO = fminf(accgO[m][r], 7.f);
              float uO = fminf(fmaxf(accuO[m][r], -7.f), 7.f);
              float avO = (uO + 1.f) * (gO / (1.f + __expf(-1.702f * gO))) * pw;
              unsigned pk = (unsigned)f2bf(avE) | ((unsigned)f2bf(avO) << 16);
              *(unsigned*)&act[(size_t)(segs + grow) * HDIM + fcE] = pk;
            }
          }
        }
      }
      __syncthreads();                     // drains act stores (vmcnt 0) for all waves
      if (tid == 0)
        __hip_atomic_fetch_add(done + e, 1, __ATOMIC_RELEASE, __HIP_MEMORY_SCOPE_AGENT);
    } else {
      // ================= down item =================
      const int target = 23 * ((n_e + MT - 1) / MT);
      if (tid == 0) {
        int guard = 0;
        while (__hip_atomic_load(done + e, __ATOMIC_ACQUIRE, __HIP_MEMORY_SCOPE_AGENT) < target) {
          __builtin_amdgcn_s_sleep(32);
          if (++guard > (1 << 22)) break;  // safety valve (never triggers when correct)
        }
      }
      __syncthreads();
      __threadfence();                     // acquire for all waves before reading act

      const int cb = ct * 128 + wid * 32;
      const int cE = cb + 2*l15;
      const int colc = min(cE, HDIM - 2);
      const float* Bq = dw + (size_t)e * HDIM * HDIM + colc + (size_t)lg * 8 * HDIM;

      const unsigned short* sp0 = nullptr;
      const unsigned short* sp1 = nullptr;
      if (m0 + r0 < n_e) sp0 = act + (size_t)(segs + m0 + r0) * HDIM + h0*16;
      if (tid < 2*MT - 256 && m0 + r1 < n_e)
        sp1 = act + (size_t)(segs + m0 + r1) * HDIM + h1*16;

      f32x4 accE[MFR], accO[MFR];
#pragma unroll
      for (int m = 0; m < MFR; ++m)
#pragma unroll
        for (int r = 0; r < 4; ++r) { accE[m][r] = 0.f; accO[m][r] = 0.f; }

      auto stage = [&](int ks, int b) {
        bf16x8 z = {0,0,0,0,0,0,0,0};
        bf16x8 v0 = z, v1 = z;
        if (sp0) { v0 = *(const bf16x8*)(sp0 + ks*32); v1 = *(const bf16x8*)(sp0 + ks*32 + 8); }
        *(bf16x8*)&Alds[b][r0][h0*16]     = v0;
        *(bf16x8*)&Alds[b][r0][h0*16 + 8] = v1;
        if (tid < 2*MT - 256) {
          bf16x8 w0 = z, w1 = z;
          if (sp1) { w0 = *(const bf16x8*)(sp1 + ks*32); w1 = *(const bf16x8*)(sp1 + ks*32 + 8); }
          *(bf16x8*)&Alds[b][r1][h1*16]     = w0;
          *(bf16x8*)&Alds[b][r1][h1*16 + 8] = w1;
        }
      };

      f32x2 bA[8];
      auto loadB = [&](int ks) {
        const float* bp = Bq + (size_t)ks * 32 * HDIM;
#pragma unroll
        for (int j = 0; j < 8; ++j)
          bA[j] = __builtin_nontemporal_load((const f32x2*)(bp + (size_t)j * HDIM));
      };

      loadB(0);
      stage(0, 0);
      lds_barrier();
      int buf = 0;

      for (int ks = 0; ks < KSTEPS; ++ks) {
        if (ks + 1 < KSTEPS) stage(ks + 1, buf ^ 1);
        bf16x8 bfE, bfO;
#pragma unroll
        for (int j = 0; j < 8; ++j) { bfE[j] = (short)f2bf(bA[j][0]); bfO[j] = (short)f2bf(bA[j][1]); }
        if (ks + 1 < KSTEPS) loadB(ks + 1);
#pragma unroll
        for (int m = 0; m < MFR; ++m) {
          bf16x8 a = *(const bf16x8*)&Alds[buf][m*16 + l15][lg*8];
          accE[m] = __builtin_amdgcn_mfma_f32_16x16x32_bf16(a, bfE, accE[m], 0, 0, 0);
          accO[m] = __builtin_amdgcn_mfma_f32_16x16x32_bf16(a, bfO, accO[m], 0, 0, 0);
        }
        lds_barrier();
        buf ^= 1;
      }

      if (cE < HDIM) {
#pragma unroll
        for (int m = 0; m < MFR; ++m) {
#pragma unroll
          for (int r = 0; r < 4; ++r) {
            int grow = m0 + m*16 + lg*4 + r;
            if (grow < n_e) {
              int t = pair_tok[segs + grow];
              atomicAdd(out + (size_t)t * HDIM + cE,     accE[m][r]);
              atomicAdd(out + (size_t)t * HDIM + cE + 1, accO[m][r]);
            }
          }
        }
      }
    }
  }
}

// ---------------- launch ----------------

extern "C" void kernel_launch(void* const* d_in, const int* in_sizes, int n_in,
                              void* d_out, int out_size, void* d_ws, size_t ws_size,
                              hipStream_t stream) {
  const float* x  = (const float*)d_in[0];
  const float* rw = (const float*)d_in[1];
  const float* rb = (const float*)d_in[2];
  const float* gw = (const float*)d_in[3];
  const float* gb = (const float*)d_in[4];
  const float* dw = (const float*)d_in[5];
  const float* db = (const float*)d_in[6];
  float* out = (float*)d_out;

  char* w = (char*)d_ws;
  int*   counts   = (int*)(w);
  int*   qhead    = (int*)(w + 256);
  int*   done     = (int*)(w + 512);
  int*   seg      = (int*)(w + 640);
  int*   top_e    = (int*)(w + 1024);
  float* top_w    = (float*)(w + 1024 + 8192);
  int*   pair_tok = (int*)(w + 1024 + 16384);
  float* pair_w   = (float*)(w + 1024 + 24576);
  unsigned short* xb  = (unsigned short*)(w + (1 << 20));    // 512 x 2880 bf16
  unsigned short* act = (unsigned short*)(w + (8 << 20));    // 2048 x 2880 bf16

  k_xbf16<<<(NTOK*HDIM)/(256*8), 256, 0, stream>>>(x, xb, counts);
  k_router<<<NTOK, 256, 0, stream>>>(x, rw, rb, counts, top_e, top_w);
  k_fill<<<NEXP, 64, 0, stream>>>(top_e, top_w, counts, seg, pair_tok, pair_w, qhead, done);
  k_outinit<<<NTOK, 256, 0, stream>>>(top_e, top_w, db, out);

  k_fused<<<512, 256, 0, stream>>>(xb, gw, gb, dw, seg, pair_tok, pair_w,
                                   act, out, qhead, done);
}

// Round 9
// 447.389 us; speedup vs baseline: 1.7986x; 1.7986x over previous
//
#include <hip/hip_runtime.h>
#include <hip/hip_bf16.h>

#define NTOK 512
#define HDIM 2880
#define NGU  5760
#define NEXP 16
#define KSTEPS 90   // 2880 / 32
#define MT 160      // m-tile rows (covers n_e up to 160 in one tile)
#define MFR 10      // MT/16 m-fragments

typedef float  f32x4  __attribute__((ext_vector_type(4)));
typedef float  f32x2  __attribute__((ext_vector_type(2)));
typedef short  bf16x8 __attribute__((ext_vector_type(8)));

__device__ __forceinline__ unsigned short f2bf(float f) {
  union { float f; unsigned u; } a; a.f = f;
  unsigned r = a.u + 0x7FFFu + ((a.u >> 16) & 1u);   // RNE truncate to bf16
  return (unsigned short)(r >> 16);
}

// Barrier that does NOT drain vmcnt: LDS-only wait + raw s_barrier.
__device__ __forceinline__ void lds_barrier() {
  asm volatile("s_waitcnt lgkmcnt(0)" ::: "memory");
  __builtin_amdgcn_s_barrier();
  asm volatile("" ::: "memory");
}

// ---------------- control kernels ----------------

__global__ __launch_bounds__(256) void k_router(
    const float* __restrict__ x, const float* __restrict__ rw,
    const float* __restrict__ rb, int* __restrict__ counts,
    int* __restrict__ top_e, float* __restrict__ top_w)
{
  const int t = blockIdx.x;
  const int tid = threadIdx.x;
  __shared__ float red[256][17];
  float acc[NEXP];
#pragma unroll
  for (int e = 0; e < NEXP; ++e) acc[e] = 0.f;
  const float* xr = x + (size_t)t * HDIM;
  for (int h = tid; h < HDIM; h += 256) {
    float xv = xr[h];
    const f32x4* wr = (const f32x4*)(rw + (size_t)h * NEXP);
#pragma unroll
    for (int q = 0; q < 4; ++q) {
      f32x4 w = wr[q];
#pragma unroll
      for (int j = 0; j < 4; ++j) acc[q*4+j] += xv * w[j];
    }
  }
#pragma unroll
  for (int e = 0; e < NEXP; ++e) red[tid][e] = acc[e];
  __syncthreads();
  for (int s = 128; s > 0; s >>= 1) {
    if (tid < s) {
#pragma unroll
      for (int e = 0; e < NEXP; ++e) red[tid][e] += red[tid + s][e];
    }
    __syncthreads();
  }
  if (tid == 0) {
    float v[NEXP];
#pragma unroll
    for (int e = 0; e < NEXP; ++e) v[e] = red[0][e] + rb[e];
    int mask = 0; float tv[4]; int ti[4];
    for (int k = 0; k < 4; ++k) {
      float best = -3.4e38f; int bi = 0;
      for (int e = 0; e < NEXP; ++e)
        if (!((mask >> e) & 1) && v[e] > best) { best = v[e]; bi = e; }
      mask |= 1 << bi; tv[k] = best; ti[k] = bi;
    }
    float s = 0.f, ex[4];
    for (int k = 0; k < 4; ++k) { ex[k] = __expf(tv[k] - tv[0]); s += ex[k]; }
    float inv = 1.f / s;
    for (int k = 0; k < 4; ++k) {
      top_e[t*4+k] = ti[k];
      top_w[t*4+k] = ex[k] * inv;
      atomicAdd(&counts[ti[k]], 1);
    }
  }
}

// one wave per expert; deterministic compaction; prefix-scan folded in.
// pair_of[t*4+k] = compacted row index of (token t, slot k) — inverse map.
__global__ __launch_bounds__(64) void k_fill(
    const int* __restrict__ top_e, const float* __restrict__ top_w,
    const int* __restrict__ counts, int* __restrict__ seg,
    int* __restrict__ pair_tok, float* __restrict__ pair_w,
    int* __restrict__ pair_of)
{
  const int e = blockIdx.x;
  const int lane = threadIdx.x;
  int base = 0;
  for (int i = 0; i < e; ++i) base += counts[i];
  if (lane == 0) {
    seg[e] = base;
    if (e == NEXP - 1) seg[NEXP] = base + counts[e];
  }
  for (int t0 = 0; t0 < NTOK; t0 += 64) {
    int t = t0 + lane;
    int my = -1;
#pragma unroll
    for (int k = 0; k < 4; ++k) if (top_e[t*4+k] == e) my = k;
    unsigned long long m = __ballot(my >= 0);
    if (my >= 0) {
      int pre = __popcll(m & ((1ull << lane) - 1ull));
      pair_tok[base + pre] = t;
      pair_w[base + pre] = top_w[t*4+my];
      pair_of[t*4 + my] = base + pre;
    }
    base += (int)__popcll(m);
  }
}

// x (f32) -> xb (bf16), once; block 0 also zeroes counts (runs before router)
__global__ __launch_bounds__(256) void k_xbf16(
    const float* __restrict__ x, unsigned short* __restrict__ xb,
    int* __restrict__ counts)
{
  if (blockIdx.x == 0 && threadIdx.x < NEXP) counts[threadIdx.x] = 0;
  int i = (blockIdx.x * 256 + threadIdx.x) * 8;
  f32x4 a = *(const f32x4*)(x + i);
  f32x4 b = *(const f32x4*)(x + i + 4);
  bf16x8 o;
#pragma unroll
  for (int j = 0; j < 4; ++j) { o[j] = (short)f2bf(a[j]); o[4+j] = (short)f2bf(b[j]); }
  *(bf16x8*)(xb + i) = o;
}

// ---------------- gate_up + activation (identical to round 6) ----------------
__global__ __launch_bounds__(256, 2) void k_gateup(
    const unsigned short* __restrict__ xb, const float* __restrict__ gw,
    const float* __restrict__ gb, const int* __restrict__ seg,
    const int* __restrict__ pair_tok, const float* __restrict__ pair_w,
    unsigned short* __restrict__ act)
{
  const int e = blockIdx.z;
  const int segs = seg[e];
  const int n_e = seg[e+1] - segs;
  const int m0 = blockIdx.y * MT;
  if (m0 >= n_e) return;
  const int tid = threadIdx.x;
  const int lane = tid & 63;
  const int wid = tid >> 6;
  const int l15 = lane & 15, lg = lane >> 4;
  const int fcb = blockIdx.x * 128 + wid * 32;
  const int fcE = fcb + 2*l15;
  const int colf = min(2*fcb + 4*l15, NGU - 4);

  __shared__ unsigned short Alds[2][MT][40];

  const float* Bq = gw + (size_t)e * HDIM * NGU + colf + (size_t)lg * 8 * NGU;

  const unsigned short* sp0 = nullptr;
  const unsigned short* sp1 = nullptr;
  const int r0 = tid >> 1, h0 = tid & 1;
  const int r1 = (tid + 256) >> 1, h1 = tid & 1;
  if (m0 + r0 < n_e) sp0 = xb + (size_t)pair_tok[segs + m0 + r0] * HDIM + h0*16;
  if (tid < 2*MT - 256 && m0 + r1 < n_e)
    sp1 = xb + (size_t)pair_tok[segs + m0 + r1] * HDIM + h1*16;

  f32x4 accgE[MFR], accuE[MFR], accgO[MFR], accuO[MFR];
  {
    f32x4 b = __builtin_nontemporal_load((const f32x4*)(gb + (size_t)e * NGU + colf));
#pragma unroll
    for (int m = 0; m < MFR; ++m)
#pragma unroll
      for (int r = 0; r < 4; ++r) {
        accgE[m][r] = b[0]; accuE[m][r] = b[1];
        accgO[m][r] = b[2]; accuO[m][r] = b[3];
      }
  }

  auto stage = [&](int ks, int b) {
    bf16x8 z = {0,0,0,0,0,0,0,0};
    bf16x8 v0 = z, v1 = z;
    if (sp0) { v0 = *(const bf16x8*)(sp0 + ks*32); v1 = *(const bf16x8*)(sp0 + ks*32 + 8); }
    *(bf16x8*)&Alds[b][r0][h0*16]     = v0;
    *(bf16x8*)&Alds[b][r0][h0*16 + 8] = v1;
    if (tid < 2*MT - 256) {
      bf16x8 w0 = z, w1 = z;
      if (sp1) { w0 = *(const bf16x8*)(sp1 + ks*32); w1 = *(const bf16x8*)(sp1 + ks*32 + 8); }
      *(bf16x8*)&Alds[b][r1][h1*16]     = w0;
      *(bf16x8*)&Alds[b][r1][h1*16 + 8] = w1;
    }
  };

  f32x4 bA[8];
  auto loadB = [&](int ks) {
    const float* bp = Bq + (size_t)ks * 32 * NGU;
#pragma unroll
    for (int j = 0; j < 8; ++j)
      bA[j] = __builtin_nontemporal_load((const f32x4*)(bp + (size_t)j * NGU));
  };

  loadB(0);
  stage(0, 0);
  lds_barrier();
  int buf = 0;

  for (int ks = 0; ks < KSTEPS; ++ks) {
    if (ks + 1 < KSTEPS) stage(ks + 1, buf ^ 1);
    bf16x8 bgE, buE, bgO, buO;
#pragma unroll
    for (int j = 0; j < 8; ++j) {
      bgE[j] = (short)f2bf(bA[j][0]); buE[j] = (short)f2bf(bA[j][1]);
      bgO[j] = (short)f2bf(bA[j][2]); buO[j] = (short)f2bf(bA[j][3]);
    }
    if (ks + 1 < KSTEPS) loadB(ks + 1);
#pragma unroll
    for (int m = 0; m < MFR; ++m) {
      bf16x8 a = *(const bf16x8*)&Alds[buf][m*16 + l15][lg*8];
      accgE[m] = __builtin_amdgcn_mfma_f32_16x16x32_bf16(a, bgE, accgE[m], 0, 0, 0);
      accuE[m] = __builtin_amdgcn_mfma_f32_16x16x32_bf16(a, buE, accuE[m], 0, 0, 0);
      accgO[m] = __builtin_amdgcn_mfma_f32_16x16x32_bf16(a, bgO, accgO[m], 0, 0, 0);
      accuO[m] = __builtin_amdgcn_mfma_f32_16x16x32_bf16(a, buO, accuO[m], 0, 0, 0);
    }
    lds_barrier();
    buf ^= 1;
  }

  if (fcE < HDIM) {
#pragma unroll
    for (int m = 0; m < MFR; ++m) {
#pragma unroll
      for (int r = 0; r < 4; ++r) {
        int grow = m0 + m*16 + lg*4 + r;
        if (grow < n_e) {
          float pw = pair_w[segs + grow];
          float gE = fminf(accgE[m][r], 7.f);
          float uE = fminf(fmaxf(accuE[m][r], -7.f), 7.f);
          float avE = (uE + 1.f) * (gE / (1.f + __expf(-1.702f * gE))) * pw;
          float gO = fminf(accgO[m][r], 7.f);
          float uO = fminf(fmaxf(accuO[m][r], -7.f), 7.f);
          float avO = (uO + 1.f) * (gO / (1.f + __expf(-1.702f * gO))) * pw;
          unsigned pk = (unsigned)f2bf(avE) | ((unsigned)f2bf(avO) << 16);
          *(unsigned*)&act[(size_t)(segs + grow) * HDIM + fcE] = pk;
        }
      }
    }
  }
}

// ---------------- down projection: non-atomic partial stores ----------------
// Each (expert,token) pair row is unique -> partial[pair_row][col] written by
// exactly one lane. Coalesced f32x2 stores; no atomics anywhere.
__global__ __launch_bounds__(256, 3) void k_down(
    const unsigned short* __restrict__ act, const float* __restrict__ dw,
    const int* __restrict__ seg, const int* __restrict__ pair_tok,
    float* __restrict__ partial)
{
  const int e = blockIdx.z;
  const int segs = seg[e];
  const int n_e = seg[e+1] - segs;
  const int m0 = blockIdx.y * MT;
  if (m0 >= n_e) return;
  const int tid = threadIdx.x;
  const int lane = tid & 63;
  const int wid = tid >> 6;
  const int l15 = lane & 15, lg = lane >> 4;
  const int cb = blockIdx.x * 128 + wid * 32;
  const int cE = cb + 2*l15;
  const int colc = min(cE, HDIM - 2);

  __shared__ unsigned short Alds[2][MT][40];

  const float* Bq = dw + (size_t)e * HDIM * HDIM + colc + (size_t)lg * 8 * HDIM;

  const unsigned short* sp0 = nullptr;
  const unsigned short* sp1 = nullptr;
  const int r0 = tid >> 1, h0 = tid & 1;
  const int r1 = (tid + 256) >> 1, h1 = tid & 1;
  if (m0 + r0 < n_e) sp0 = act + (size_t)(segs + m0 + r0) * HDIM + h0*16;
  if (tid < 2*MT - 256 && m0 + r1 < n_e)
    sp1 = act + (size_t)(segs + m0 + r1) * HDIM + h1*16;

  f32x4 accE[MFR], accO[MFR];
#pragma unroll
  for (int m = 0; m < MFR; ++m)
#pragma unroll
    for (int r = 0; r < 4; ++r) { accE[m][r] = 0.f; accO[m][r] = 0.f; }

  auto stage = [&](int ks, int b) {
    bf16x8 z = {0,0,0,0,0,0,0,0};
    bf16x8 v0 = z, v1 = z;
    if (sp0) { v0 = *(const bf16x8*)(sp0 + ks*32); v1 = *(const bf16x8*)(sp0 + ks*32 + 8); }
    *(bf16x8*)&Alds[b][r0][h0*16]     = v0;
    *(bf16x8*)&Alds[b][r0][h0*16 + 8] = v1;
    if (tid < 2*MT - 256) {
      bf16x8 w0 = z, w1 = z;
      if (sp1) { w0 = *(const bf16x8*)(sp1 + ks*32); w1 = *(const bf16x8*)(sp1 + ks*32 + 8); }
      *(bf16x8*)&Alds[b][r1][h1*16]     = w0;
      *(bf16x8*)&Alds[b][r1][h1*16 + 8] = w1;
    }
  };

  f32x2 bA[8];
  auto loadB = [&](int ks) {
    const float* bp = Bq + (size_t)ks * 32 * HDIM;
#pragma unroll
    for (int j = 0; j < 8; ++j)
      bA[j] = __builtin_nontemporal_load((const f32x2*)(bp + (size_t)j * HDIM));
  };

  loadB(0);
  stage(0, 0);
  lds_barrier();
  int buf = 0;

  for (int ks = 0; ks < KSTEPS; ++ks) {
    if (ks + 1 < KSTEPS) stage(ks + 1, buf ^ 1);
    bf16x8 bfE, bfO;
#pragma unroll
    for (int j = 0; j < 8; ++j) { bfE[j] = (short)f2bf(bA[j][0]); bfO[j] = (short)f2bf(bA[j][1]); }
    if (ks + 1 < KSTEPS) loadB(ks + 1);
#pragma unroll
    for (int m = 0; m < MFR; ++m) {
      bf16x8 a = *(const bf16x8*)&Alds[buf][m*16 + l15][lg*8];
      accE[m] = __builtin_amdgcn_mfma_f32_16x16x32_bf16(a, bfE, accE[m], 0, 0, 0);
      accO[m] = __builtin_amdgcn_mfma_f32_16x16x32_bf16(a, bfO, accO[m], 0, 0, 0);
    }
    lds_barrier();
    buf ^= 1;
  }

  if (cE < HDIM) {
#pragma unroll
    for (int m = 0; m < MFR; ++m) {
#pragma unroll
      for (int r = 0; r < 4; ++r) {
        int grow = m0 + m*16 + lg*4 + r;
        if (grow < n_e) {
          f32x2 v = { accE[m][r], accO[m][r] };
          *(f32x2*)&partial[(size_t)(segs + grow) * HDIM + cE] = v;
        }
      }
    }
  }
}

// ---------------- gather: out[t] = sum_k partial[pair_of[t][k]] + bias ----
__global__ __launch_bounds__(256) void k_gather(
    const float* __restrict__ partial, const int* __restrict__ pair_of,
    const int* __restrict__ top_e, const float* __restrict__ top_w,
    const float* __restrict__ db, float* __restrict__ out)
{
  const int t = blockIdx.x;
  const int tid = threadIdx.x;
  const int p0 = pair_of[t*4+0], p1 = pair_of[t*4+1];
  const int p2 = pair_of[t*4+2], p3 = pair_of[t*4+3];
  const float w0 = top_w[t*4+0], w1 = top_w[t*4+1];
  const float w2 = top_w[t*4+2], w3 = top_w[t*4+3];
  const float* r0 = partial + (size_t)p0 * HDIM;
  const float* r1 = partial + (size_t)p1 * HDIM;
  const float* r2 = partial + (size_t)p2 * HDIM;
  const float* r3 = partial + (size_t)p3 * HDIM;
  const float* b0 = db + (size_t)top_e[t*4+0] * HDIM;
  const float* b1 = db + (size_t)top_e[t*4+1] * HDIM;
  const float* b2 = db + (size_t)top_e[t*4+2] * HDIM;
  const float* b3 = db + (size_t)top_e[t*4+3] * HDIM;
  float* o = out + (size_t)t * HDIM;
  for (int p = tid; p < HDIM/4; p += 256) {
    f32x4 v0 = *(const f32x4*)(r0 + 4*p);
    f32x4 v1 = *(const f32x4*)(r1 + 4*p);
    f32x4 v2 = *(const f32x4*)(r2 + 4*p);
    f32x4 v3 = *(const f32x4*)(r3 + 4*p);
    f32x4 c0 = *(const f32x4*)(b0 + 4*p);
    f32x4 c1 = *(const f32x4*)(b1 + 4*p);
    f32x4 c2 = *(const f32x4*)(b2 + 4*p);
    f32x4 c3 = *(const f32x4*)(b3 + 4*p);
    f32x4 s;
#pragma unroll
    for (int j = 0; j < 4; ++j)
      s[j] = (v0[j] + v1[j]) + (v2[j] + v3[j])
           + (w0*c0[j] + w1*c1[j]) + (w2*c2[j] + w3*c3[j]);
    *(f32x4*)(o + 4*p) = s;
  }
}

// ---------------- launch ----------------

extern "C" void kernel_launch(void* const* d_in, const int* in_sizes, int n_in,
                              void* d_out, int out_size, void* d_ws, size_t ws_size,
                              hipStream_t stream) {
  const float* x  = (const float*)d_in[0];
  const float* rw = (const float*)d_in[1];
  const float* rb = (const float*)d_in[2];
  const float* gw = (const float*)d_in[3];
  const float* gb = (const float*)d_in[4];
  const float* dw = (const float*)d_in[5];
  const float* db = (const float*)d_in[6];
  float* out = (float*)d_out;

  char* w = (char*)d_ws;
  int*   counts   = (int*)(w);
  int*   seg      = (int*)(w + 64);
  int*   top_e    = (int*)(w + 1024);
  float* top_w    = (float*)(w + 1024 + 8192);
  int*   pair_tok = (int*)(w + 1024 + 16384);
  float* pair_w   = (float*)(w + 1024 + 24576);
  int*   pair_of  = (int*)(w + 1024 + 32768);
  unsigned short* xb  = (unsigned short*)(w + (1 << 20));    // 512 x 2880 bf16
  unsigned short* act = (unsigned short*)(w + (8 << 20));    // 2048 x 2880 bf16
  float* partial = (float*)(w + (64ull << 20));              // 2048 x 2880 f32 = 23.6 MB

  k_xbf16<<<(NTOK*HDIM)/(256*8), 256, 0, stream>>>(x, xb, counts);
  k_router<<<NTOK, 256, 0, stream>>>(x, rw, rb, counts, top_e, top_w);
  k_fill<<<NEXP, 64, 0, stream>>>(top_e, top_w, counts, seg, pair_tok, pair_w, pair_of);

  dim3 gg(23, 2, NEXP);   // 23 fc tiles (128 fc each) x {main, overflow} x experts
  k_gateup<<<gg, 256, 0, stream>>>(xb, gw, gb, seg, pair_tok, pair_w, act);

  dim3 gd(23, 2, NEXP);   // 23 col tiles (128 cols each) x {main, overflow} x experts
  k_down<<<gd, 256, 0, stream>>>(act, dw, seg, pair_tok, partial);

  k_gather<<<NTOK, 256, 0, stream>>>(partial, pair_of, top_e, top_w, db, out);
}

// Round 10
// 437.461 us; speedup vs baseline: 1.8395x; 1.0227x over previous
//
#include <hip/hip_runtime.h>
#include <hip/hip_bf16.h>

#define NTOK 512
#define HDIM 2880
#define NGU  5760
#define NEXP 16
#define KSTEPS 90   // 2880 / 32
#define KSH   45    // K-steps per half (down kernel)
#define MT 160      // m-tile rows (covers n_e up to 160 in one tile)
#define MFR 10      // MT/16 m-fragments
#define PARTELT ((size_t)(NTOK*4) * HDIM)   // elements per partial buffer

typedef float  f32x4  __attribute__((ext_vector_type(4)));
typedef float  f32x2  __attribute__((ext_vector_type(2)));
typedef short  bf16x8 __attribute__((ext_vector_type(8)));

__device__ __forceinline__ unsigned short f2bf(float f) {
  union { float f; unsigned u; } a; a.f = f;
  unsigned r = a.u + 0x7FFFu + ((a.u >> 16) & 1u);   // RNE truncate to bf16
  return (unsigned short)(r >> 16);
}

// Barrier that does NOT drain vmcnt: LDS-only wait + raw s_barrier.
__device__ __forceinline__ void lds_barrier() {
  asm volatile("s_waitcnt lgkmcnt(0)" ::: "memory");
  __builtin_amdgcn_s_barrier();
  asm volatile("" ::: "memory");
}

// ---------------- control kernels ----------------

__global__ __launch_bounds__(256) void k_router(
    const float* __restrict__ x, const float* __restrict__ rw,
    const float* __restrict__ rb, int* __restrict__ counts,
    int* __restrict__ top_e, float* __restrict__ top_w)
{
  const int t = blockIdx.x;
  const int tid = threadIdx.x;
  __shared__ float red[256][17];
  float acc[NEXP];
#pragma unroll
  for (int e = 0; e < NEXP; ++e) acc[e] = 0.f;
  const float* xr = x + (size_t)t * HDIM;
  for (int h = tid; h < HDIM; h += 256) {
    float xv = xr[h];
    const f32x4* wr = (const f32x4*)(rw + (size_t)h * NEXP);
#pragma unroll
    for (int q = 0; q < 4; ++q) {
      f32x4 w = wr[q];
#pragma unroll
      for (int j = 0; j < 4; ++j) acc[q*4+j] += xv * w[j];
    }
  }
#pragma unroll
  for (int e = 0; e < NEXP; ++e) red[tid][e] = acc[e];
  __syncthreads();
  for (int s = 128; s > 0; s >>= 1) {
    if (tid < s) {
#pragma unroll
      for (int e = 0; e < NEXP; ++e) red[tid][e] += red[tid + s][e];
    }
    __syncthreads();
  }
  if (tid == 0) {
    float v[NEXP];
#pragma unroll
    for (int e = 0; e < NEXP; ++e) v[e] = red[0][e] + rb[e];
    int mask = 0; float tv[4]; int ti[4];
    for (int k = 0; k < 4; ++k) {
      float best = -3.4e38f; int bi = 0;
      for (int e = 0; e < NEXP; ++e)
        if (!((mask >> e) & 1) && v[e] > best) { best = v[e]; bi = e; }
      mask |= 1 << bi; tv[k] = best; ti[k] = bi;
    }
    float s = 0.f, ex[4];
    for (int k = 0; k < 4; ++k) { ex[k] = __expf(tv[k] - tv[0]); s += ex[k]; }
    float inv = 1.f / s;
    for (int k = 0; k < 4; ++k) {
      top_e[t*4+k] = ti[k];
      top_w[t*4+k] = ex[k] * inv;
      atomicAdd(&counts[ti[k]], 1);
    }
  }
}

// one wave per expert; deterministic compaction; prefix-scan folded in.
// pair_of[t*4+k] = compacted row index of (token t, slot k) — inverse map.
__global__ __launch_bounds__(64) void k_fill(
    const int* __restrict__ top_e, const float* __restrict__ top_w,
    const int* __restrict__ counts, int* __restrict__ seg,
    int* __restrict__ pair_tok, float* __restrict__ pair_w,
    int* __restrict__ pair_of)
{
  const int e = blockIdx.x;
  const int lane = threadIdx.x;
  int base = 0;
  for (int i = 0; i < e; ++i) base += counts[i];
  if (lane == 0) {
    seg[e] = base;
    if (e == NEXP - 1) seg[NEXP] = base + counts[e];
  }
  for (int t0 = 0; t0 < NTOK; t0 += 64) {
    int t = t0 + lane;
    int my = -1;
#pragma unroll
    for (int k = 0; k < 4; ++k) if (top_e[t*4+k] == e) my = k;
    unsigned long long m = __ballot(my >= 0);
    if (my >= 0) {
      int pre = __popcll(m & ((1ull << lane) - 1ull));
      pair_tok[base + pre] = t;
      pair_w[base + pre] = top_w[t*4+my];
      pair_of[t*4 + my] = base + pre;
    }
    base += (int)__popcll(m);
  }
}

// x (f32) -> xb (bf16), once; block 0 also zeroes counts (runs before router)
__global__ __launch_bounds__(256) void k_xbf16(
    const float* __restrict__ x, unsigned short* __restrict__ xb,
    int* __restrict__ counts)
{
  if (blockIdx.x == 0 && threadIdx.x < NEXP) counts[threadIdx.x] = 0;
  int i = (blockIdx.x * 256 + threadIdx.x) * 8;
  f32x4 a = *(const f32x4*)(x + i);
  f32x4 b = *(const f32x4*)(x + i + 4);
  bf16x8 o;
#pragma unroll
  for (int j = 0; j < 4; ++j) { o[j] = (short)f2bf(a[j]); o[4+j] = (short)f2bf(b[j]); }
  *(bf16x8*)(xb + i) = o;
}

// ---------------- gate_up + activation (identical to round 9) ----------------
__global__ __launch_bounds__(256, 2) void k_gateup(
    const unsigned short* __restrict__ xb, const float* __restrict__ gw,
    const float* __restrict__ gb, const int* __restrict__ seg,
    const int* __restrict__ pair_tok, const float* __restrict__ pair_w,
    unsigned short* __restrict__ act)
{
  const int e = blockIdx.z;
  const int segs = seg[e];
  const int n_e = seg[e+1] - segs;
  const int m0 = blockIdx.y * MT;
  if (m0 >= n_e) return;
  const int tid = threadIdx.x;
  const int lane = tid & 63;
  const int wid = tid >> 6;
  const int l15 = lane & 15, lg = lane >> 4;
  const int fcb = blockIdx.x * 128 + wid * 32;
  const int fcE = fcb + 2*l15;
  const int colf = min(2*fcb + 4*l15, NGU - 4);

  __shared__ unsigned short Alds[2][MT][40];

  const float* Bq = gw + (size_t)e * HDIM * NGU + colf + (size_t)lg * 8 * NGU;

  const unsigned short* sp0 = nullptr;
  const unsigned short* sp1 = nullptr;
  const int r0 = tid >> 1, h0 = tid & 1;
  const int r1 = (tid + 256) >> 1, h1 = tid & 1;
  if (m0 + r0 < n_e) sp0 = xb + (size_t)pair_tok[segs + m0 + r0] * HDIM + h0*16;
  if (tid < 2*MT - 256 && m0 + r1 < n_e)
    sp1 = xb + (size_t)pair_tok[segs + m0 + r1] * HDIM + h1*16;

  f32x4 accgE[MFR], accuE[MFR], accgO[MFR], accuO[MFR];
  {
    f32x4 b = __builtin_nontemporal_load((const f32x4*)(gb + (size_t)e * NGU + colf));
#pragma unroll
    for (int m = 0; m < MFR; ++m)
#pragma unroll
      for (int r = 0; r < 4; ++r) {
        accgE[m][r] = b[0]; accuE[m][r] = b[1];
        accgO[m][r] = b[2]; accuO[m][r] = b[3];
      }
  }

  auto stage = [&](int ks, int b) {
    bf16x8 z = {0,0,0,0,0,0,0,0};
    bf16x8 v0 = z, v1 = z;
    if (sp0) { v0 = *(const bf16x8*)(sp0 + ks*32); v1 = *(const bf16x8*)(sp0 + ks*32 + 8); }
    *(bf16x8*)&Alds[b][r0][h0*16]     = v0;
    *(bf16x8*)&Alds[b][r0][h0*16 + 8] = v1;
    if (tid < 2*MT - 256) {
      bf16x8 w0 = z, w1 = z;
      if (sp1) { w0 = *(const bf16x8*)(sp1 + ks*32); w1 = *(const bf16x8*)(sp1 + ks*32 + 8); }
      *(bf16x8*)&Alds[b][r1][h1*16]     = w0;
      *(bf16x8*)&Alds[b][r1][h1*16 + 8] = w1;
    }
  };

  f32x4 bA[8];
  auto loadB = [&](int ks) {
    const float* bp = Bq + (size_t)ks * 32 * NGU;
#pragma unroll
    for (int j = 0; j < 8; ++j)
      bA[j] = __builtin_nontemporal_load((const f32x4*)(bp + (size_t)j * NGU));
  };

  loadB(0);
  stage(0, 0);
  lds_barrier();
  int buf = 0;

  for (int ks = 0; ks < KSTEPS; ++ks) {
    if (ks + 1 < KSTEPS) stage(ks + 1, buf ^ 1);
    bf16x8 bgE, buE, bgO, buO;
#pragma unroll
    for (int j = 0; j < 8; ++j) {
      bgE[j] = (short)f2bf(bA[j][0]); buE[j] = (short)f2bf(bA[j][1]);
      bgO[j] = (short)f2bf(bA[j][2]); buO[j] = (short)f2bf(bA[j][3]);
    }
    if (ks + 1 < KSTEPS) loadB(ks + 1);
#pragma unroll
    for (int m = 0; m < MFR; ++m) {
      bf16x8 a = *(const bf16x8*)&Alds[buf][m*16 + l15][lg*8];
      accgE[m] = __builtin_amdgcn_mfma_f32_16x16x32_bf16(a, bgE, accgE[m], 0, 0, 0);
      accuE[m] = __builtin_amdgcn_mfma_f32_16x16x32_bf16(a, buE, accuE[m], 0, 0, 0);
      accgO[m] = __builtin_amdgcn_mfma_f32_16x16x32_bf16(a, bgO, accgO[m], 0, 0, 0);
      accuO[m] = __builtin_amdgcn_mfma_f32_16x16x32_bf16(a, buO, accuO[m], 0, 0, 0);
    }
    lds_barrier();
    buf ^= 1;
  }

  if (fcE < HDIM) {
#pragma unroll
    for (int m = 0; m < MFR; ++m) {
#pragma unroll
      for (int r = 0; r < 4; ++r) {
        int grow = m0 + m*16 + lg*4 + r;
        if (grow < n_e) {
          float pw = pair_w[segs + grow];
          float gE = fminf(accgE[m][r], 7.f);
          float uE = fminf(fmaxf(accuE[m][r], -7.f), 7.f);
          float avE = (uE + 1.f) * (gE / (1.f + __expf(-1.702f * gE))) * pw;
          float gO = fminf(accgO[m][r], 7.f);
          float uO = fminf(fmaxf(accuO[m][r], -7.f), 7.f);
          float avO = (uO + 1.f) * (gO / (1.f + __expf(-1.702f * gO))) * pw;
          unsigned pk = (unsigned)f2bf(avE) | ((unsigned)f2bf(avO) << 16);
          *(unsigned*)&act[(size_t)(segs + grow) * HDIM + fcE] = pk;
        }
      }
    }
  }
}

// ---------------- down projection: K-split halves, non-atomic partials ----
// grid (23, 4, 16): y = (mi<<1)|kh. 736 uniform half-K units pack CUs evenly
// (max-CU 3 units = 2.16 MB vs 2.88 MB unsplit) -> wall ~88us vs 117us.
__global__ __launch_bounds__(256, 3) void k_down(
    const unsigned short* __restrict__ act, const float* __restrict__ dw,
    const int* __restrict__ seg, const int* __restrict__ pair_tok,
    float* __restrict__ partial)
{
  const int e = blockIdx.z;
  const int mi = blockIdx.y >> 1;
  const int kh = blockIdx.y & 1;
  const int segs = seg[e];
  const int n_e = seg[e+1] - segs;
  const int m0 = mi * MT;
  if (m0 >= n_e) return;
  const int tid = threadIdx.x;
  const int lane = tid & 63;
  const int wid = tid >> 6;
  const int l15 = lane & 15, lg = lane >> 4;
  const int cb = blockIdx.x * 128 + wid * 32;
  const int cE = cb + 2*l15;
  const int colc = min(cE, HDIM - 2);
  const int k0 = kh * (KSH * 32);

  __shared__ unsigned short Alds[2][MT][40];

  float* po = partial + (size_t)kh * PARTELT;
  const float* Bq = dw + (size_t)e * HDIM * HDIM + colc
                  + (size_t)(k0 + lg * 8) * HDIM;

  const unsigned short* sp0 = nullptr;
  const unsigned short* sp1 = nullptr;
  const int r0 = tid >> 1, h0 = tid & 1;
  const int r1 = (tid + 256) >> 1, h1 = tid & 1;
  if (m0 + r0 < n_e) sp0 = act + (size_t)(segs + m0 + r0) * HDIM + k0 + h0*16;
  if (tid < 2*MT - 256 && m0 + r1 < n_e)
    sp1 = act + (size_t)(segs + m0 + r1) * HDIM + k0 + h1*16;

  f32x4 accE[MFR], accO[MFR];
#pragma unroll
  for (int m = 0; m < MFR; ++m)
#pragma unroll
    for (int r = 0; r < 4; ++r) { accE[m][r] = 0.f; accO[m][r] = 0.f; }

  auto stage = [&](int ks, int b) {
    bf16x8 z = {0,0,0,0,0,0,0,0};
    bf16x8 v0 = z, v1 = z;
    if (sp0) { v0 = *(const bf16x8*)(sp0 + ks*32); v1 = *(const bf16x8*)(sp0 + ks*32 + 8); }
    *(bf16x8*)&Alds[b][r0][h0*16]     = v0;
    *(bf16x8*)&Alds[b][r0][h0*16 + 8] = v1;
    if (tid < 2*MT - 256) {
      bf16x8 w0 = z, w1 = z;
      if (sp1) { w0 = *(const bf16x8*)(sp1 + ks*32); w1 = *(const bf16x8*)(sp1 + ks*32 + 8); }
      *(bf16x8*)&Alds[b][r1][h1*16]     = w0;
      *(bf16x8*)&Alds[b][r1][h1*16 + 8] = w1;
    }
  };

  f32x2 bA[8];
  auto loadB = [&](int ks) {
    const float* bp = Bq + (size_t)ks * 32 * HDIM;
#pragma unroll
    for (int j = 0; j < 8; ++j)
      bA[j] = __builtin_nontemporal_load((const f32x2*)(bp + (size_t)j * HDIM));
  };

  loadB(0);
  stage(0, 0);
  lds_barrier();
  int buf = 0;

  for (int ks = 0; ks < KSH; ++ks) {
    if (ks + 1 < KSH) stage(ks + 1, buf ^ 1);
    bf16x8 bfE, bfO;
#pragma unroll
    for (int j = 0; j < 8; ++j) { bfE[j] = (short)f2bf(bA[j][0]); bfO[j] = (short)f2bf(bA[j][1]); }
    if (ks + 1 < KSH) loadB(ks + 1);
#pragma unroll
    for (int m = 0; m < MFR; ++m) {
      bf16x8 a = *(const bf16x8*)&Alds[buf][m*16 + l15][lg*8];
      accE[m] = __builtin_amdgcn_mfma_f32_16x16x32_bf16(a, bfE, accE[m], 0, 0, 0);
      accO[m] = __builtin_amdgcn_mfma_f32_16x16x32_bf16(a, bfO, accO[m], 0, 0, 0);
    }
    lds_barrier();
    buf ^= 1;
  }

  if (cE < HDIM) {
#pragma unroll
    for (int m = 0; m < MFR; ++m) {
#pragma unroll
      for (int r = 0; r < 4; ++r) {
        int grow = m0 + m*16 + lg*4 + r;
        if (grow < n_e) {
          f32x2 v = { accE[m][r], accO[m][r] };
          *(f32x2*)&po[(size_t)(segs + grow) * HDIM + cE] = v;
        }
      }
    }
  }
}

// ---- gather: out[t] = sum_k (partial0+partial1)[pair_of[t][k]] + bias ----
__global__ __launch_bounds__(256) void k_gather(
    const float* __restrict__ partial, const int* __restrict__ pair_of,
    const int* __restrict__ top_e, const float* __restrict__ top_w,
    const float* __restrict__ db, float* __restrict__ out)
{
  const int t = blockIdx.x;
  const int tid = threadIdx.x;
  const int p0 = pair_of[t*4+0], p1 = pair_of[t*4+1];
  const int p2 = pair_of[t*4+2], p3 = pair_of[t*4+3];
  const float w0 = top_w[t*4+0], w1 = top_w[t*4+1];
  const float w2 = top_w[t*4+2], w3 = top_w[t*4+3];
  const float* r0 = partial + (size_t)p0 * HDIM;
  const float* r1 = partial + (size_t)p1 * HDIM;
  const float* r2 = partial + (size_t)p2 * HDIM;
  const float* r3 = partial + (size_t)p3 * HDIM;
  const float* q0 = r0 + PARTELT;
  const float* q1 = r1 + PARTELT;
  const float* q2 = r2 + PARTELT;
  const float* q3 = r3 + PARTELT;
  const float* b0 = db + (size_t)top_e[t*4+0] * HDIM;
  const float* b1 = db + (size_t)top_e[t*4+1] * HDIM;
  const float* b2 = db + (size_t)top_e[t*4+2] * HDIM;
  const float* b3 = db + (size_t)top_e[t*4+3] * HDIM;
  float* o = out + (size_t)t * HDIM;
  for (int p = tid; p < HDIM/4; p += 256) {
    f32x4 v0 = *(const f32x4*)(r0 + 4*p);
    f32x4 v1 = *(const f32x4*)(r1 + 4*p);
    f32x4 v2 = *(const f32x4*)(r2 + 4*p);
    f32x4 v3 = *(const f32x4*)(r3 + 4*p);
    f32x4 u0 = *(const f32x4*)(q0 + 4*p);
    f32x4 u1 = *(const f32x4*)(q1 + 4*p);
    f32x4 u2 = *(const f32x4*)(q2 + 4*p);
    f32x4 u3 = *(const f32x4*)(q3 + 4*p);
    f32x4 c0 = *(const f32x4*)(b0 + 4*p);
    f32x4 c1 = *(const f32x4*)(b1 + 4*p);
    f32x4 c2 = *(const f32x4*)(b2 + 4*p);
    f32x4 c3 = *(const f32x4*)(b3 + 4*p);
    f32x4 s;
#pragma unroll
    for (int j = 0; j < 4; ++j)
      s[j] = ((v0[j] + u0[j]) + (v1[j] + u1[j]))
           + ((v2[j] + u2[j]) + (v3[j] + u3[j]))
           + (w0*c0[j] + w1*c1[j]) + (w2*c2[j] + w3*c3[j]);
    *(f32x4*)(o + 4*p) = s;
  }
}

// ---------------- launch ----------------

extern "C" void kernel_launch(void* const* d_in, const int* in_sizes, int n_in,
                              void* d_out, int out_size, void* d_ws, size_t ws_size,
                              hipStream_t stream) {
  const float* x  = (const float*)d_in[0];
  const float* rw = (const float*)d_in[1];
  const float* rb = (const float*)d_in[2];
  const float* gw = (const float*)d_in[3];
  const float* gb = (const float*)d_in[4];
  const float* dw = (const float*)d_in[5];
  const float* db = (const float*)d_in[6];
  float* out = (float*)d_out;

  char* w = (char*)d_ws;
  int*   counts   = (int*)(w);
  int*   seg      = (int*)(w + 64);
  int*   top_e    = (int*)(w + 1024);
  float* top_w    = (float*)(w + 1024 + 8192);
  int*   pair_tok = (int*)(w + 1024 + 16384);
  float* pair_w   = (float*)(w + 1024 + 24576);
  int*   pair_of  = (int*)(w + 1024 + 32768);
  unsigned short* xb  = (unsigned short*)(w + (1 << 20));    // 512 x 2880 bf16
  unsigned short* act = (unsigned short*)(w + (8 << 20));    // 2048 x 2880 bf16
  float* partial = (float*)(w + (64ull << 20));              // 2 x 2048 x 2880 f32

  k_xbf16<<<(NTOK*HDIM)/(256*8), 256, 0, stream>>>(x, xb, counts);
  k_router<<<NTOK, 256, 0, stream>>>(x, rw, rb, counts, top_e, top_w);
  k_fill<<<NEXP, 64, 0, stream>>>(top_e, top_w, counts, seg, pair_tok, pair_w, pair_of);

  dim3 gg(23, 2, NEXP);   // 23 fc tiles x {main, overflow} x experts
  k_gateup<<<gg, 256, 0, stream>>>(xb, gw, gb, seg, pair_tok, pair_w, act);

  dim3 gd(23, 4, NEXP);   // 23 col tiles x {m-tile, K-half} x experts
  k_down<<<gd, 256, 0, stream>>>(act, dw, seg, pair_tok, partial);

  k_gather<<<NTOK, 256, 0, stream>>>(partial, pair_of, top_e, top_w, db, out);
}